// Round 1
// 517.237 us; speedup vs baseline: 1.0462x; 1.0462x over previous
//
#include <hip/hip_runtime.h>
#include <math.h>
#include <stdint.h>

#define T_   512
#define H_   1024
#define I_   512
#define E_   64
#define K_   6
#define G_   8
#define TG_  3
#define EB_  80      // 64 routed + 16 shared-expert (half x token-eighth) blocks

typedef _Float16 h8 __attribute__((ext_vector_type(8)));
typedef _Float16 h4v __attribute__((ext_vector_type(4)));
typedef float    f4 __attribute__((ext_vector_type(4)));

// ---------------- router: sigmoid + group-limited top-k (verified) ------
__global__ __launch_bounds__(64) void router_k(
    const float* __restrict__ x, const float* __restrict__ gw,
    int* __restrict__ cnt, int* __restrict__ tlist, float* __restrict__ wlist)
{
  const int t   = blockIdx.x;
  const int tid = threadIdx.x;
  __shared__ float sx[H_];
  __shared__ float sc[E_];

  for (int h4 = tid; h4 < H_/4; h4 += 64)
    ((float4*)sx)[h4] = ((const float4*)(x + (size_t)t*H_))[h4];
  __syncthreads();

  const float* wr = gw + (size_t)tid * H_;
  float acc = 0.f;
  for (int h = 0; h < H_; h += 4) {
    float4 xv = *(const float4*)(sx + h);
    float4 wv = *(const float4*)(wr + h);
    acc = fmaf(xv.x, wv.x, acc); acc = fmaf(xv.y, wv.y, acc);
    acc = fmaf(xv.z, wv.z, acc); acc = fmaf(xv.w, wv.w, acc);
  }
  sc[tid] = 1.f / (1.f + expf(-acc));
  __syncthreads();

  if (tid == 0) {
    float gs[G_];
    #pragma unroll
    for (int g = 0; g < G_; g++) {
      float m = sc[g*8];
      #pragma unroll
      for (int j = 1; j < 8; j++) m = fmaxf(m, sc[g*8+j]);
      gs[g] = m;
    }
    unsigned gp = 0;
    for (int r = 0; r < TG_; r++) {
      int best = 0; float bv = -1e30f;
      for (int g = 0; g < G_; g++)
        if (!((gp >> g) & 1) && gs[g] > bv) { bv = gs[g]; best = g; }
      gp |= 1u << best;
    }
    int   eidx[K_]; float ew[K_];
    unsigned long long em = 0ull;
    float wsum = 0.f;
    for (int r = 0; r < K_; r++) {
      int best = 0; float bv = -1e30f;
      for (int e = 0; e < E_; e++) {
        if (!((gp >> (e >> 3)) & 1)) continue;
        if ((em >> e) & 1ull) continue;
        if (sc[e] > bv) { bv = sc[e]; best = e; }
      }
      em |= 1ull << best; eidx[r] = best; ew[r] = bv; wsum += bv;
    }
    const float inv = 2.5f / (wsum + 1e-20f);
    for (int r = 0; r < K_; r++) {
      int e = eidx[r];
      int pos = atomicAdd(&cnt[e], 1);
      tlist[e*T_ + pos] = (t << 13) | (t*K_ + r);   // hmid row = t*6+rank
      wlist[e*T_ + pos] = ew[r] * inv;
    }
  }
}

// ---------------- pseudo-expert token lists (shared halves) -------------
__global__ void pseudo_init_k(int* cnt, int* tlist, float* wlist) {
  int s = blockIdx.x*256 + threadIdx.x;       // 0..1023
  if (s == 0) { cnt[64] = T_; cnt[65] = T_; }
  if (s < 1024) {
    int e = 64 + (s >> 9);
    int t = s & 511;
    tlist[e*T_ + t] = (t << 13) | (3072 + s); // rows 3072..4095
    wlist[e*T_ + t] = 1.0f;
  }
}

// ---------------- x -> f16 prep ----------------------------------------
__global__ __launch_bounds__(256) void xh_prep_k(
    const float* __restrict__ x, _Float16* __restrict__ xh)
{
  int i = blockIdx.x*256 + threadIdx.x;       // float4 index
  float4 v = ((const float4*)x)[i];
  h4v o = { (_Float16)v.x, (_Float16)v.y, (_Float16)v.z, (_Float16)v.w };
  *(h4v*)(xh + (size_t)i*4) = o;
}

// ---- expert-block descriptor: eb<64 -> routed; eb>=64 -> shared slice ---
// shared: 2 halves x 8 token-eighths (64 tokens each) => single M-pass/block
__device__ __forceinline__ void eb_decode(int eb, const int* cnt,
                                          int& e, int& lo, int& hi) {
  if (eb < E_) { e = eb; lo = 0; hi = cnt[e]; }
  else { int q = (eb - E_) & 7; e = E_ + ((eb - E_) >> 3); lo = q*64; hi = lo + 64; }
}

// async 16B global -> LDS (wave-uniform LDS base + lane*16 by HW)
__device__ __forceinline__ void gld16(const int* g, void* l) {
  __builtin_amdgcn_global_load_lds(
      (const __attribute__((address_space(1))) void*)g,
      (__attribute__((address_space(3))) void*)l, 16, 0, 0);
}

// two int4 (8 int32 weights) -> f16 fragment with scale folded
__device__ __forceinline__ h8 cvt8(int4 a, int4 b, float s) {
  union { _Float16 f[8]; h8 v; } t;
  t.f[0]=(_Float16)((float)a.x*s); t.f[1]=(_Float16)((float)a.y*s);
  t.f[2]=(_Float16)((float)a.z*s); t.f[3]=(_Float16)((float)a.w*s);
  t.f[4]=(_Float16)((float)b.x*s); t.f[5]=(_Float16)((float)b.y*s);
  t.f[6]=(_Float16)((float)b.z*s); t.f[7]=(_Float16)((float)b.w*s);
  return t.v;
}

#define PIPE_SYNC() do { \
    asm volatile("s_waitcnt vmcnt(0)" ::: "memory"); \
    __builtin_amdgcn_s_barrier(); \
    __builtin_amdgcn_sched_barrier(0); } while (0)

// ---------------- gate+up MFMA: hmid[row, ic*64..+64) -------------------
// 2-phase global_load_lds pipeline. Tile = 64 i-rows x 64 ints (BK=64),
// both matrices staged -> 32KB/tile, double-buffered (64KB LDS, 2 blk/CU).
// LDS layout: row = 64 ints = 16 chunks of 16B; chunk swizzle c ^= (row&7)
// (applied on BOTH global-source side and ds_read side).
#define NKT_G 16
__global__ __launch_bounds__(256, 2) void gateup_k(
    const _Float16* __restrict__ xh,
    const int* __restrict__ wg, const float* __restrict__ sg,
    const int* __restrict__ wu, const float* __restrict__ su,
    const int* __restrict__ shwg, const float* __restrict__ shsg,
    const int* __restrict__ shwu, const float* __restrict__ shsu,
    const int* __restrict__ cnt, const int* __restrict__ tlist,
    const float* __restrict__ wlist,
    _Float16* __restrict__ hmid)
{
  const int ic = blockIdx.x;                  // i-chunk of 64
  const int eb = blockIdx.y;
  int e, lo, hi;
  eb_decode(eb, cnt, e, lo, hi);
  if (hi <= lo) return;

  const int tid  = threadIdx.x;
  const int lane = tid & 63;
  const int wv   = tid >> 6;
  const int mr   = lane & 15;
  const int quad = lane >> 4;

  const int *wgb, *wub; const float *sgp, *sup; int sib;
  if (e < E_) {
    wgb = wg + (size_t)e*I_*H_;  wub = wu + (size_t)e*I_*H_;
    sgp = sg + e*32;  sup = su + e*32;  sib = ic >> 1;
  } else {
    int hf = e - E_;
    wgb = shwg + (size_t)hf*512*H_;  wub = shwu + (size_t)hf*512*H_;
    sgp = shsg;  sup = shsu;  sib = hf*4 + (ic >> 1);
  }
  const int r0base = ic*64;

  __shared__ int   ldsw[2][2][4096];          // [buf][g/u][row*64+int] 64KB
  __shared__ int   stok[64];
  __shared__ int   srow[64];
  __shared__ float swt[64];

  // stage one K-tile (both matrices): 8 global_load_lds per wave
  auto stage = [&](int buf, int kt) {
    const int k0 = kt * 64;
    #pragma unroll
    for (int i = 0; i < 4; i++) {
      const int rl  = i*16 + wv*4 + (lane >> 4);        // tile row 0..63
      const int csw = (lane & 15) ^ (rl & 7);           // swizzled 16B chunk
      const size_t go = (size_t)(r0base + rl)*H_ + k0 + csw*4;
      gld16(wgb + go, &ldsw[buf][0][(i*16 + wv*4)*64]);
      gld16(wub + go, &ldsw[buf][1][(i*16 + wv*4)*64]);
    }
  };

  const int rr = wv*16 + mr;                  // this lane's tile row
  const int sw = rr & 7;

  for (int base = lo; base < hi; base += 64) {
    __syncthreads();
    if (tid < 64) {
      int slot = base + tid;
      if (slot < hi) {
        int ent = tlist[e*T_ + slot];
        stok[tid] = ent >> 13; srow[tid] = ent & 8191; swt[tid] = wlist[e*T_ + slot];
      } else { stok[tid] = -1; srow[tid] = 0; swt[tid] = 0.f; }
    }
    __syncthreads();

    const _Float16* ax[4];
    #pragma unroll
    for (int mt = 0; mt < 4; mt++) {
      int tok = stok[mt*16 + mr];
      ax[mt] = xh + (size_t)(tok < 0 ? 0 : tok) * H_ + quad*8;
    }

    f4 accg[4], accu[4];
    #pragma unroll
    for (int mt = 0; mt < 4; mt++) { accg[mt] = (f4){0.f,0.f,0.f,0.f}; accu[mt] = accg[mt]; }

    stage(0, 0);
    PIPE_SYNC();

    int cur = 0;
    for (int kt = 0; kt < NKT_G; kt++) {
      // A-fragments to regs FIRST (older than next stage => consuming them
      // never drains the in-flight stage)
      h8 avv[4][2];
      #pragma unroll
      for (int mt = 0; mt < 4; mt++) {
        avv[mt][0] = *(const h8*)(ax[mt] + kt*64);
        avv[mt][1] = *(const h8*)(ax[mt] + kt*64 + 32);
      }
      __builtin_amdgcn_sched_barrier(0);
      if (kt < NKT_G-1) stage(cur ^ 1, kt + 1);

      const float sg_ = sgp[sib*8 + (kt >> 1)];
      const float su_ = sup[sib*8 + (kt >> 1)];
      const int* lg = &ldsw[cur][0][0];
      const int* lu = &ldsw[cur][1][0];
      #pragma unroll
      for (int ktl = 0; ktl < 2; ktl++) {
        const int c0 = ktl*8 + quad*2;
        int4 g0 = *(const int4*)(lg + rr*64 + (( c0   ) ^ sw)*4);
        int4 g1 = *(const int4*)(lg + rr*64 + (((c0+1)) ^ sw)*4);
        int4 u0 = *(const int4*)(lu + rr*64 + (( c0   ) ^ sw)*4);
        int4 u1 = *(const int4*)(lu + rr*64 + (((c0+1)) ^ sw)*4);
        h8 bg = cvt8(g0, g1, sg_);
        h8 bu = cvt8(u0, u1, su_);
        #pragma unroll
        for (int mt = 0; mt < 4; mt++) {
          accg[mt] = __builtin_amdgcn_mfma_f32_16x16x32_f16(avv[mt][ktl], bg, accg[mt], 0,0,0);
          accu[mt] = __builtin_amdgcn_mfma_f32_16x16x32_f16(avv[mt][ktl], bu, accu[mt], 0,0,0);
        }
      }
      if (kt < NKT_G-1) { PIPE_SYNC(); cur ^= 1; }
    }

    // epilogue: silu(g)*u*w -> hmid   (C/D: col=lane&15 (i), row=quad*4+r)
    const int icol = ic*64 + rr;
    #pragma unroll
    for (int mt = 0; mt < 4; mt++) {
      #pragma unroll
      for (int r = 0; r < 4; r++) {
        int sl = mt*16 + quad*4 + r;
        if (stok[sl] >= 0) {
          float g = accg[mt][r];
          float m = g / (1.f + expf(-g)) * accu[mt][r] * swt[sl];
          hmid[(size_t)srow[sl]*I_ + icol] = (_Float16)m;
        }
      }
    }
  }
}

// ---------------- down MFMA: out[t, hc*128..+128) += hmid @ Wd ----------
// 2-phase pipeline. Tile = 64 i-rows x 128 h-ints = 32KB, double-buffered.
// Staging reads CONTIGUOUS 512B rows (fixes the 4KB-stride scalar loads).
// LDS row = 128 ints = 32 chunks of 16B; chunk swizzle c ^= ((row>>3)&1)<<2.
#define NKT_D 8
__global__ __launch_bounds__(256, 2) void down_k(
    const int* __restrict__ wd, const float* __restrict__ sd,
    const int* __restrict__ shwd, const float* __restrict__ shsd,
    const int* __restrict__ cnt, const int* __restrict__ tlist,
    const _Float16* __restrict__ hmid, float* __restrict__ out)
{
  const int hc = blockIdx.x;                  // h-chunk of 128
  const int eb = blockIdx.y;
  int e, lo, hi;
  eb_decode(eb, cnt, e, lo, hi);
  if (hi <= lo) return;

  const int tid  = threadIdx.x;
  const int lane = tid & 63;
  const int wv   = tid >> 6;
  const int mr   = lane & 15;
  const int quad = lane >> 4;

  const int* wb; const float* sdp; int sib0;
  if (e < E_) { wb = wd + (size_t)e*I_*H_;        sdp = sd + e*32;  sib0 = 0; }
  else { int hf = e - E_; wb = shwd + (size_t)hf*512*H_; sdp = shsd; sib0 = hf*4; }

  __shared__ int ldsd[2][8192];               // [buf][row*128+int] 64KB
  __shared__ int stok[64];
  __shared__ int srow[64];

  auto stage = [&](int buf, int kt) {
    const int i0 = kt*64;
    #pragma unroll
    for (int s = 0; s < 8; s++) {
      const int rl  = s*8 + wv*2 + (lane >> 5);         // tile row 0..63
      const int csw = (lane & 31) ^ (((rl >> 3) & 1) << 2);
      gld16(wb + (size_t)(i0 + rl)*H_ + hc*128 + csw*4,
            &ldsd[buf][(s*8 + wv*2)*128]);
    }
  };

  const int hcol0 = hc*128 + wv*32 + mr;      // p-tile 1 at +16
  const int swd   = (quad & 1) << 2;          // read-side chunk swizzle
  const int cd0   = wv*32 + mr;
  const int cd1   = cd0 + 16;
  const int off0  = (((cd0 >> 2) ^ swd) << 2) + (cd0 & 3);
  const int off1  = (((cd1 >> 2) ^ swd) << 2) + (cd1 & 3);

  for (int base = lo; base < hi; base += 64) {
    __syncthreads();
    if (tid < 64) {
      int slot = base + tid;
      if (slot < hi) {
        int ent = tlist[e*T_ + slot];
        stok[tid] = ent >> 13; srow[tid] = ent & 8191;
      } else { stok[tid] = -1; srow[tid] = 0; }
    }
    __syncthreads();

    const _Float16* ap[4];
    #pragma unroll
    for (int mt = 0; mt < 4; mt++)
      ap[mt] = hmid + (size_t)srow[mt*16 + mr]*I_ + quad*8;

    f4 a0[4], a1[4];
    #pragma unroll
    for (int mt = 0; mt < 4; mt++) { a0[mt] = (f4){0.f,0.f,0.f,0.f}; a1[mt] = a0[mt]; }

    stage(0, 0);
    PIPE_SYNC();

    int cur = 0;
    for (int kt = 0; kt < NKT_D; kt++) {
      h8 avv[4][2];
      #pragma unroll
      for (int mt = 0; mt < 4; mt++) {
        avv[mt][0] = *(const h8*)(ap[mt] + kt*64);
        avv[mt][1] = *(const h8*)(ap[mt] + kt*64 + 32);
      }
      __builtin_amdgcn_sched_barrier(0);
      if (kt < NKT_D-1) stage(cur ^ 1, kt + 1);

      const float s = sdp[(sib0 + (kt >> 1))*8 + hc];
      const int* lb = &ldsd[cur][0];
      #pragma unroll
      for (int ktl = 0; ktl < 2; ktl++) {
        union { _Float16 f[8]; h8 v; } b0, b1;
        #pragma unroll
        for (int j = 0; j < 8; j++) {
          const int r = ktl*32 + quad*8 + j;
          b0.f[j] = (_Float16)((float)lb[r*128 + off0] * s);
          b1.f[j] = (_Float16)((float)lb[r*128 + off1] * s);
        }
        #pragma unroll
        for (int mt = 0; mt < 4; mt++) {
          a0[mt] = __builtin_amdgcn_mfma_f32_16x16x32_f16(avv[mt][ktl], b0.v, a0[mt], 0,0,0);
          a1[mt] = __builtin_amdgcn_mfma_f32_16x16x32_f16(avv[mt][ktl], b1.v, a1[mt], 0,0,0);
        }
      }
      if (kt < NKT_D-1) { PIPE_SYNC(); cur ^= 1; }
    }

    #pragma unroll
    for (int mt = 0; mt < 4; mt++) {
      #pragma unroll
      for (int p = 0; p < 2; p++) {
        f4 av2 = (p == 0) ? a0[mt] : a1[mt];
        const int hcol = hcol0 + p*16;
        #pragma unroll
        for (int r = 0; r < 4; r++) {
          int sl = mt*16 + quad*4 + r;
          int t = stok[sl];
          if (t >= 0) atomicAdd(out + (size_t)t*H_ + hcol, av2[r]);
        }
      }
    }
  }
}

// ---------------- launch ----------------
extern "C" void kernel_launch(void* const* d_in, const int* in_sizes, int n_in,
                              void* d_out, int out_size, void* d_ws, size_t ws_size,
                              hipStream_t stream) {
  (void)in_sizes; (void)n_in; (void)ws_size;
  const float* x    = (const float*)d_in[0];
  const float* gw   = (const float*)d_in[1];
  const int*   wg   = (const int*  )d_in[2];
  const float* sg   = (const float*)d_in[3];
  const int*   wu   = (const int*  )d_in[4];
  const float* su   = (const float*)d_in[5];
  const int*   wd   = (const int*  )d_in[6];
  const float* sd   = (const float*)d_in[7];
  const int*   shwg = (const int*  )d_in[8];
  const float* shsg = (const float*)d_in[9];
  const int*   shwu = (const int*  )d_in[10];
  const float* shsu = (const float*)d_in[11];
  const int*   shwd = (const int*  )d_in[12];
  const float* shsd = (const float*)d_in[13];
  float* out = (float*)d_out;

  char* ws = (char*)d_ws;
  int*      cnt   = (int*     ) ws;                              // 66 ints
  int*      tlist = (int*     )(ws + 1024);                      // 66*512
  float*    wlist = (float*   )(ws + 1024 + 66*T_*4);            // 66*512
  _Float16* hmid  = (_Float16*)(ws + 1024 + 2*66*T_*4);          // 4096*512 f16
  _Float16* xh    = (_Float16*)(ws + 1024 + 2*66*T_*4 + 4096*I_*2); // 512*1024 f16

  hipMemsetAsync(cnt, 0, 1024, stream);
  hipMemsetAsync(d_out, 0, (size_t)out_size * sizeof(float), stream);
  xh_prep_k<<<T_*H_/1024, 256, 0, stream>>>(x, xh);
  router_k<<<T_, 64, 0, stream>>>(x, gw, cnt, tlist, wlist);
  pseudo_init_k<<<4, 256, 0, stream>>>(cnt, tlist, wlist);
  gateup_k<<<dim3(8, EB_), 256, 0, stream>>>(xh, wg, sg, wu, su,
                                             shwg, shsg, shwu, shsu,
                                             cnt, tlist, wlist, hmid);
  down_k<<<dim3(8, EB_), 256, 0, stream>>>(wd, sd, shwd, shsd,
                                           cnt, tlist, hmid, out);
}